// Round 2
// baseline (447.993 us; speedup 1.0000x reference)
//
#include <hip/hip_runtime.h>

#define NB 1024   // batches
#define NN 4096   // rows per batch
#define P  16     // wdim
#define TPB 256
#define RPT 4                                 // float4 segments per thread per chunk
#define NCHUNK 16                             // chunks: TPB*RPT*NCHUNK = 16384 = NN*4
#define SEGB (NN * 4)                         // float4 segments per batch

typedef float f4 __attribute__((ext_vector_type(4)));

// ---------------------------------------------------------------------------
// One block per batch. 16 threads build M[b] in LDS once (forward substitution
// of the Bartlett factor; first z-chunk loads already in flight above it),
// then all 256 threads stream the batch's 4096x16 z through the quad-shfl
// apply in 16 ping-pong-pipelined chunks. Loads/stores are lane-consecutive
// float4 -> every memory instruction covers a contiguous 1 KB span.
//   M row j = rsqrt(||col_j(inv A)||^2) * col_j(inv A),
//   A = tril(A_noise,-1) + diag(sqrt(chisq)).
// Grid: 1024 blocks x 256 threads; __launch_bounds__(256,4) caps VGPR at 128
// -> 4 blocks/CU -> whole grid co-resident in ~one generation.
// ---------------------------------------------------------------------------
__global__ __launch_bounds__(TPB, 4) void prior_w_fused(
    const float* __restrict__ A_noise, const float* __restrict__ chisq,
    const float* __restrict__ z, float* __restrict__ w) {
  __shared__ __align__(16) float Msh[P][P];   // M rows, contiguous for f4 reads
  __shared__ float As[P][P + 1];              // staged A (padded)
  __shared__ float colS[P][P + 1];            // per-column solve workspace
  __shared__ float dS[P];                     // 1/sqrt(chisq_i)

  const int tid   = threadIdx.x;
  const int b     = blockIdx.x;
  const int q     = tid & 3;                  // output quarter owned by lane
  const int quad0 = tid & ~3;                 // first lane of aligned quad

  const size_t base = (size_t)b * SEGB + tid; // f4 segment index, chunk 0
  const f4* zf4 = (const f4*)z;
  f4* wf4 = (f4*)w;

  // ---- prefetch chunk 0; these fly during the solve ----
  f4 zA[RPT], zB[RPT];
#pragma unroll
  for (int k = 0; k < RPT; ++k)
    zA[k] = __builtin_nontemporal_load(zf4 + base + (size_t)k * TPB);

  // ---- stage A (1 float/thread, coalesced) and diagonal rsqrts ----
  As[tid >> 4][tid & 15] = A_noise[(size_t)b * (P * P) + tid];
  if (tid < P) dS[tid] = rsqrtf(chisq[(size_t)b * P + tid]);
  __syncthreads();

  // ---- 16 threads: column j of inv(A) by forward substitution (once/batch) --
  if (tid < P) {
    const int j = tid;
    const float cj = dS[j];                   // B[j][j] = 1/d_j
    colS[j][j] = cj;
    float n2 = cj * cj;
    for (int i = j + 1; i < P; ++i) {
      float s = 0.f;
      for (int k = j; k < i; ++k) s += As[i][k] * colS[j][k];
      const float ci = -s * dS[i];
      colS[j][i] = ci;
      n2 += ci * ci;
    }
    const float sc = rsqrtf(n2);
    for (int i = 0; i < j; ++i) Msh[j][i] = 0.f;
    for (int i = j; i < P; ++i) Msh[j][i] = sc * colS[j][i];
  }
  __syncthreads();

  // ---- lane's 4 M rows (quarter q): 16 f4 = 64 VGPRs ----
  f4 Mr[4][4];
#pragma unroll
  for (int c = 0; c < 4; ++c)
#pragma unroll
    for (int s = 0; s < 4; ++s)
      Mr[c][s] = *(const f4*)&Msh[4 * q + c][4 * s];

  // ---- compute+store one chunk held in registers (static indexing only) ----
  auto do_chunk = [&](const f4 (&zv)[RPT], int c) {
    const size_t sb = base + (size_t)c * (TPB * RPT);
#pragma unroll
    for (int k = 0; k < RPT; ++k) {
      f4 row[4];
#pragma unroll
      for (int d = 0; d < 4; ++d) {
        row[d].x = __shfl(zv[k].x, quad0 + d, 64);
        row[d].y = __shfl(zv[k].y, quad0 + d, 64);
        row[d].z = __shfl(zv[k].z, quad0 + d, 64);
        row[d].w = __shfl(zv[k].w, quad0 + d, 64);
      }
      f4 o;
#pragma unroll
      for (int cc = 0; cc < 4; ++cc) {
        float acc = 0.f;
#pragma unroll
        for (int s = 0; s < 4; ++s) {
          acc = fmaf(Mr[cc][s].x, row[s].x, acc);
          acc = fmaf(Mr[cc][s].y, row[s].y, acc);
          acc = fmaf(Mr[cc][s].z, row[s].z, acc);
          acc = fmaf(Mr[cc][s].w, row[s].w, acc);
        }
        if (cc == 0) o.x = acc; else if (cc == 1) o.y = acc;
        else if (cc == 2) o.z = acc; else o.w = acc;
      }
      __builtin_nontemporal_store(o, wf4 + sb + (size_t)k * TPB);
    }
  };

  // ---- ping-pong pipelined chunk loop (zA/zB statically indexed) ----
#pragma unroll 1
  for (int c = 0; c < NCHUNK; c += 2) {
    if (c + 1 < NCHUNK) {                     // prefetch chunk c+1 into zB
      const size_t sb = base + (size_t)(c + 1) * (TPB * RPT);
#pragma unroll
      for (int k = 0; k < RPT; ++k)
        zB[k] = __builtin_nontemporal_load(zf4 + sb + (size_t)k * TPB);
    }
    do_chunk(zA, c);
    if (c + 2 < NCHUNK) {                     // prefetch chunk c+2 into zA
      const size_t sb = base + (size_t)(c + 2) * (TPB * RPT);
#pragma unroll
      for (int k = 0; k < RPT; ++k)
        zA[k] = __builtin_nontemporal_load(zf4 + sb + (size_t)k * TPB);
    }
    do_chunk(zB, c + 1);
  }
}

extern "C" void kernel_launch(void* const* d_in, const int* in_sizes, int n_in,
                              void* d_out, int out_size, void* d_ws, size_t ws_size,
                              hipStream_t stream) {
  const float* A_noise = (const float*)d_in[0];
  const float* chisq   = (const float*)d_in[1];
  const float* z       = (const float*)d_in[2];
  prior_w_fused<<<NB, TPB, 0, stream>>>(A_noise, chisq, z, (float*)d_out);
}

// Round 3
// 421.451 us; speedup vs baseline: 1.0630x; 1.0630x over previous
//
#include <hip/hip_runtime.h>

#define NB 1024   // batches
#define NN 4096   // rows per batch
#define P  16     // wdim
#define TPB 256
#define RPT 8                                     // float4 segments per thread
#define SEGB (NN * 4)                             // segments per batch = 16384
#define BPB  (SEGB / (TPB * RPT))                 // blocks per batch = 8

typedef float f4 __attribute__((ext_vector_type(4)));

// ---------------------------------------------------------------------------
// Fused kernel, 8 blocks per batch (8192 x 256). Each block redundantly builds
// M[b] with a FULLY UNROLLED register-resident forward substitution:
//   col[k] = 0 for k<j makes the triangular sum equal the full static sum
//   bit-exactly (fmaf(a,0,s)==s), so all loop bounds are compile-time, col[]
//   stays in VGPRs, and the ~120 As[i][k] reads are wave-uniform LDS
//   broadcasts with no dependent-load chain (solve ~0.3us vs ~6us rolled).
// Streaming apply unchanged from the 441.9us version: lane-consecutive f4
// segments (1 KB/instruction), quad-shfl row gather, nontemporal in/out.
// ---------------------------------------------------------------------------
__global__ __launch_bounds__(TPB) void prior_w_fused(
    const float* __restrict__ A_noise, const float* __restrict__ chisq,
    const float* __restrict__ z, float* __restrict__ w) {
  __shared__ __align__(16) float Msh[P][P];   // M rows, contiguous for f4 reads
  __shared__ float As[P][P + 1];              // staged A (padded)

  const int tid   = threadIdx.x;
  const int b     = blockIdx.x >> 3;
  const int chunk = blockIdx.x & 7;
  const int q     = tid & 3;                  // output quarter owned by lane
  const int quad0 = tid & ~3;                 // first lane of aligned quad

  // ---- issue all streaming loads up front; they fly during the solve ----
  const size_t segbase = (size_t)b * SEGB + (size_t)chunk * (TPB * RPT) + tid;
  const f4* zf4 = (const f4*)z;
  f4 zv[RPT];
#pragma unroll
  for (int k = 0; k < RPT; ++k)
    zv[k] = __builtin_nontemporal_load(zf4 + segbase + (size_t)k * TPB);

  // ---- stage A (1 float/thread, coalesced) ----
  As[tid >> 4][tid & 15] = A_noise[(size_t)b * (P * P) + tid];
  __syncthreads();

  // ---- 16 threads: column j of inv(A), fully unrolled, registers only ----
  if (tid < P) {
    const int j = tid;
    float d[P];                               // 1/sqrt(chisq_i); uniform loads
#pragma unroll
    for (int i = 0; i < P; ++i) d[i] = rsqrtf(chisq[(size_t)b * P + i]);
    const float cj = d[j];
    float col[P];                             // static indexing -> VGPRs
    float n2 = 0.f;
#pragma unroll
    for (int i = 0; i < P; ++i) {
      float s = 0.f;
#pragma unroll
      for (int k = 0; k < i; ++k)             // col[k]=0 for k<j: exact no-op terms
        s = fmaf(As[i][k], col[k], s);
      const float ci = -s * d[i];
      col[i] = (i > j) ? ci : ((i == j) ? cj : 0.f);
      n2 = fmaf(col[i], col[i], n2);
    }
    const float sc = rsqrtf(n2);
#pragma unroll
    for (int i = 0; i < P; ++i) Msh[j][i] = sc * col[i];  // zeros for i<j
  }
  __syncthreads();

  // ---- lane's 4 M rows (quarter q): 16 f4 = 64 VGPRs ----
  f4 Mr[4][4];
#pragma unroll
  for (int c = 0; c < 4; ++c)
#pragma unroll
    for (int s = 0; s < 4; ++s)
      Mr[c][s] = *(const f4*)&Msh[4 * q + c][4 * s];

  // ---- quad-shfl apply: fully coalesced f4 segments, 1 KB/instruction ----
  f4* wf4 = (f4*)w;
#pragma unroll
  for (int k = 0; k < RPT; ++k) {
    // gather the full 16-float z row across the aligned 4-lane quad
    f4 row[4];
#pragma unroll
    for (int d0 = 0; d0 < 4; ++d0) {
      row[d0].x = __shfl(zv[k].x, quad0 + d0, 64);
      row[d0].y = __shfl(zv[k].y, quad0 + d0, 64);
      row[d0].z = __shfl(zv[k].z, quad0 + d0, 64);
      row[d0].w = __shfl(zv[k].w, quad0 + d0, 64);
    }
    // out[c] = M[4q+c][:] . row[:]
    f4 o;
#pragma unroll
    for (int c = 0; c < 4; ++c) {
      float acc = 0.f;
#pragma unroll
      for (int s = 0; s < 4; ++s) {
        acc = fmaf(Mr[c][s].x, row[s].x, acc);
        acc = fmaf(Mr[c][s].y, row[s].y, acc);
        acc = fmaf(Mr[c][s].z, row[s].z, acc);
        acc = fmaf(Mr[c][s].w, row[s].w, acc);
      }
      if (c == 0) o.x = acc; else if (c == 1) o.y = acc;
      else if (c == 2) o.z = acc; else o.w = acc;
    }
    __builtin_nontemporal_store(o, wf4 + segbase + (size_t)k * TPB);
  }
}

extern "C" void kernel_launch(void* const* d_in, const int* in_sizes, int n_in,
                              void* d_out, int out_size, void* d_ws, size_t ws_size,
                              hipStream_t stream) {
  const float* A_noise = (const float*)d_in[0];
  const float* chisq   = (const float*)d_in[1];
  const float* z       = (const float*)d_in[2];
  prior_w_fused<<<NB * BPB, TPB, 0, stream>>>(A_noise, chisq, z, (float*)d_out);
}